// Round 2
// baseline (594.125 us; speedup 1.0000x reference)
//
#include <hip/hip_runtime.h>
#include <hip/hip_bf16.h>

#define ENC_DIM 2048
#define DEC_DIM 512
#define ATT_DIM 512
#define BATCH   128
#define NPIX    196
#define NROWS   (BATCH * NPIX)   // 25088

typedef short bf16x8 __attribute__((ext_vector_type(8)));
typedef float f32x4  __attribute__((ext_vector_type(4)));
typedef unsigned short u16x8 __attribute__((ext_vector_type(8)));

__device__ __forceinline__ unsigned short f2bf(float f) {
    union { float f; unsigned u; } v; v.f = f;
    unsigned r = v.u + 0x7fffu + ((v.u >> 16) & 1u);   // RNE
    return (unsigned short)(r >> 16);
}

// ---------------------------------------------------------------- k0:
// Wt[a][e] = bf16(W_enc[e][a])  (2048x512 -> 512x2048), LDS-tiled transpose.
__global__ void k0_transpose(const float* __restrict__ W_enc,
                             unsigned short* __restrict__ Wt) {
    __shared__ float ts[64][65];
    const int a0 = blockIdx.x * 64;      // grid.x = 8
    const int e0 = blockIdx.y * 64;      // grid.y = 32
    const int tx = threadIdx.x & 15;
    const int ty = threadIdx.x >> 4;     // 16x16 threads
    #pragma unroll
    for (int p = 0; p < 4; ++p) {
        const int e = ty + p * 16;
        const float4 v = *(const float4*)&W_enc[(size_t)(e0 + e) * ATT_DIM + a0 + tx * 4];
        ts[e][tx * 4 + 0] = v.x; ts[e][tx * 4 + 1] = v.y;
        ts[e][tx * 4 + 2] = v.z; ts[e][tx * 4 + 3] = v.w;
    }
    __syncthreads();
    #pragma unroll
    for (int p = 0; p < 4; ++p) {
        const int a = ty + p * 16;
        ushort4 u;
        u.x = f2bf(ts[tx * 4 + 0][a]);
        u.y = f2bf(ts[tx * 4 + 1][a]);
        u.z = f2bf(ts[tx * 4 + 2][a]);
        u.w = f2bf(ts[tx * 4 + 3][a]);
        *(ushort4*)&Wt[(size_t)(a0 + a) * ENC_DIM + e0 + tx * 4] = u;
    }
}

// ---------------------------------------------------------------- k1:
// att2'[b][a] = dh[b,:]@W_dec[:,a] + b_dec[a] + b_enc[a];  att[r]=b_full;
// also zero-init awe (d_out is poisoned before every call; k4 atomically adds).
__global__ void k1_att2(const float* __restrict__ dh, const float* __restrict__ W_dec,
                        const float* __restrict__ b_dec, const float* __restrict__ b_enc,
                        const float* __restrict__ b_full,
                        float* __restrict__ att2, float* __restrict__ att,
                        float* __restrict__ awe) {
    __shared__ float dhs[DEC_DIM];
    const int b = blockIdx.x, t = threadIdx.x;   // 128 blocks x 256 thr
    const f32x4 z = {0.f, 0.f, 0.f, 0.f};
    *(f32x4*)&awe[(size_t)b * ENC_DIM + t * 8]     = z;
    *(f32x4*)&awe[(size_t)b * ENC_DIM + t * 8 + 4] = z;
    dhs[t]       = dh[b * DEC_DIM + t];
    dhs[t + 256] = dh[b * DEC_DIM + t + 256];
    __syncthreads();
    float acc0 = 0.f, acc1 = 0.f;
    for (int d = 0; d < DEC_DIM; ++d) {
        const float h = dhs[d];
        acc0 += h * W_dec[d * ATT_DIM + t];
        acc1 += h * W_dec[d * ATT_DIM + t + 256];
    }
    att2[b * ATT_DIM + t]       = acc0 + b_dec[t]       + b_enc[t];
    att2[b * ATT_DIM + t + 256] = acc1 + b_dec[t + 256] + b_enc[t + 256];
    const int gid = b * 256 + t;
    if (gid < NROWS) att[gid] = b_full[0];
}

// ---------------------------------------------------------------- k2:
// Fused bf16 MFMA GEMM + relu + W_full reduction -> atomic partial scores.
// Tile 128 rows x 128 attn-cols, BK=64, register-prefetch pipeline.
// grid (4 n-tiles, 196 m-tiles).
__launch_bounds__(256, 3)
__global__ void k2_gemm(const float* __restrict__ enc, const unsigned short* __restrict__ Wt,
                        const float* __restrict__ att2, const float* __restrict__ W_full,
                        float* __restrict__ att) {
    __shared__ __align__(16) unsigned short As[128 * 72];  // 64 k + 8 pad
    __shared__ __align__(16) unsigned short Bs[128 * 72];
    __shared__ float att2s[2][128];
    __shared__ float wfs[128];

    const int t    = threadIdx.x;
    const int n0   = blockIdx.x * 128;
    const int row0 = blockIdx.y * 128;
    const int b0   = row0 / NPIX;
    const int rows_left = (b0 + 1) * NPIX - row0;   // rows in this tile with batch b0

    if (t < 128) {
        att2s[0][t] = att2[b0 * ATT_DIM + n0 + t];
        att2s[1][t] = (b0 + 1 < BATCH) ? att2[(b0 + 1) * ATT_DIM + n0 + t] : 0.f;
        wfs[t]      = W_full[n0 + t];
    }

    const int w    = t >> 6;         // wave 0..3
    const int lane = t & 63;
    const int q    = lane >> 4;      // 0..3
    const int cl   = lane & 15;
    const int wm   = (w >> 1) * 64;  // wave's row offset
    const int wn   = (w & 1) * 64;   // wave's col offset

    f32x4 acc[4][4] = {};

    // staging assignments (BK=64)
    const int ar = t >> 3;           // A row 0..31 (+32/pass), 4 passes
    const int ak = (t & 7) * 8;      // A k 0..56
    const int bn = t >> 2;           // B row 0..63 (+64/pass), 2 passes
    const int bk = (t & 3) * 16;     // B k 0..48

    const float*          encA = enc + (size_t)(row0 + ar) * ENC_DIM + ak;
    const unsigned short* WtB  = Wt  + (size_t)(n0 + bn)   * ENC_DIM + bk;

    float4 ra[4][2];
    uint4  rb[2][2];
    // prologue: prefetch K-chunk 0
    #pragma unroll
    for (int p = 0; p < 4; ++p) {
        ra[p][0] = *(const float4*)(encA + (size_t)p * 32 * ENC_DIM);
        ra[p][1] = *(const float4*)(encA + (size_t)p * 32 * ENC_DIM + 4);
    }
    #pragma unroll
    for (int p = 0; p < 2; ++p) {
        rb[p][0] = *(const uint4*)(WtB + (size_t)p * 64 * ENC_DIM);
        rb[p][1] = *(const uint4*)(WtB + (size_t)p * 64 * ENC_DIM + 8);
    }

    for (int kt = 0; kt < 32; ++kt) {
        __syncthreads();   // previous iteration's frag reads complete
        #pragma unroll
        for (int p = 0; p < 4; ++p) {
            u16x8 v;
            v[0] = f2bf(ra[p][0].x); v[1] = f2bf(ra[p][0].y);
            v[2] = f2bf(ra[p][0].z); v[3] = f2bf(ra[p][0].w);
            v[4] = f2bf(ra[p][1].x); v[5] = f2bf(ra[p][1].y);
            v[6] = f2bf(ra[p][1].z); v[7] = f2bf(ra[p][1].w);
            *(u16x8*)&As[(ar + p * 32) * 72 + ak] = v;
        }
        #pragma unroll
        for (int p = 0; p < 2; ++p) {
            *(uint4*)&Bs[(bn + p * 64) * 72 + bk]     = rb[p][0];
            *(uint4*)&Bs[(bn + p * 64) * 72 + bk + 8] = rb[p][1];
        }
        __syncthreads();   // tile visible

        if (kt < 31) {     // prefetch next K-chunk into registers (overlaps MFMA)
            const int ko = (kt + 1) * 64;
            #pragma unroll
            for (int p = 0; p < 4; ++p) {
                ra[p][0] = *(const float4*)(encA + (size_t)p * 32 * ENC_DIM + ko);
                ra[p][1] = *(const float4*)(encA + (size_t)p * 32 * ENC_DIM + ko + 4);
            }
            #pragma unroll
            for (int p = 0; p < 2; ++p) {
                rb[p][0] = *(const uint4*)(WtB + (size_t)p * 64 * ENC_DIM + ko);
                rb[p][1] = *(const uint4*)(WtB + (size_t)p * 64 * ENC_DIM + ko + 8);
            }
        }

        #pragma unroll
        for (int h = 0; h < 2; ++h) {   // two 32-wide K halves
            bf16x8 af[4], bfr[4];
            #pragma unroll
            for (int i = 0; i < 4; ++i) {
                af[i]  = *(const bf16x8*)&As[(wm + i * 16 + cl) * 72 + h * 32 + q * 8];
                bfr[i] = *(const bf16x8*)&Bs[(wn + i * 16 + cl) * 72 + h * 32 + q * 8];
            }
            #pragma unroll
            for (int mi = 0; mi < 4; ++mi)
                #pragma unroll
                for (int ni = 0; ni < 4; ++ni)
                    acc[mi][ni] = __builtin_amdgcn_mfma_f32_16x16x32_bf16(
                        af[mi], bfr[ni], acc[mi][ni], 0, 0, 0);
        }
    }

    // Epilogue: relu(att1 + att2') * W_full, reduce over this block's 128 cols.
    #pragma unroll
    for (int mi = 0; mi < 4; ++mi) {
        float rs[4];
        #pragma unroll
        for (int i = 0; i < 4; ++i) {
            const int lr  = wm + mi * 16 + q * 4 + i;         // local row
            const int sel = (lr >= rows_left) ? 1 : 0;
            float sum = 0.f;
            #pragma unroll
            for (int ni = 0; ni < 4; ++ni) {
                const int j = wn + ni * 16 + cl;              // local col 0..127
                float v = acc[mi][ni][i] + att2s[sel][j];
                v = fmaxf(v, 0.f);
                sum += v * wfs[j];
            }
            rs[i] = sum;
        }
        #pragma unroll
        for (int o = 1; o < 16; o <<= 1) {
            #pragma unroll
            for (int i = 0; i < 4; ++i) rs[i] += __shfl_xor(rs[i], o);
        }
        if (cl == 0) {
            #pragma unroll
            for (int i = 0; i < 4; ++i) {
                const int r = row0 + wm + mi * 16 + q * 4 + i;
                atomicAdd(&att[r], rs[i]);
            }
        }
    }
}

// ---------------------------------------------------------------- k3:
// softmax over P=196, in place. 128 blocks x 256 thr.
__global__ void k3_softmax(float* __restrict__ att_alpha) {
    __shared__ float red[4];
    const int b = blockIdx.x, t = threadIdx.x;
    const int w = t >> 6, lane = t & 63;
    const float x = (t < NPIX) ? att_alpha[b * NPIX + t] : -INFINITY;
    float m = x;
    #pragma unroll
    for (int o = 32; o >= 1; o >>= 1) m = fmaxf(m, __shfl_xor(m, o));
    if (lane == 0) red[w] = m;
    __syncthreads();
    m = fmaxf(fmaxf(red[0], red[1]), fmaxf(red[2], red[3]));
    const float e = (t < NPIX) ? __expf(x - m) : 0.f;
    float s = e;
    #pragma unroll
    for (int o = 32; o >= 1; o >>= 1) s += __shfl_xor(s, o);
    __syncthreads();
    if (lane == 0) red[w] = s;
    __syncthreads();
    s = red[0] + red[1] + red[2] + red[3];
    if (t < NPIX) att_alpha[b * NPIX + t] = e / s;
}

// ---------------------------------------------------------------- k4:
// awe[b][e] += sum_{p in split} alpha[b][p] * enc[b][p][e].
// grid (2 e-chunks, 4 p-splits, 128 b) = 1024 blocks; awe zeroed by k1.
__global__ void k4_awe(const float* __restrict__ enc, const float* __restrict__ alpha,
                       float* __restrict__ awe) {
    __shared__ float as[49];
    const int b  = blockIdx.z;
    const int p0 = blockIdx.y * 49;
    const int e0 = blockIdx.x * 1024 + threadIdx.x * 4;
    if (threadIdx.x < 49) as[threadIdx.x] = alpha[b * NPIX + p0 + threadIdx.x];
    __syncthreads();
    const float* base = enc + ((size_t)b * NPIX + p0) * ENC_DIM + e0;
    f32x4 a0 = {0,0,0,0}, a1 = {0,0,0,0}, a2 = {0,0,0,0}, a3 = {0,0,0,0};
    #pragma unroll 4
    for (int p = 0; p < 48; p += 4) {
        const f32x4 v0 = *(const f32x4*)(base + (size_t)(p + 0) * ENC_DIM);
        const f32x4 v1 = *(const f32x4*)(base + (size_t)(p + 1) * ENC_DIM);
        const f32x4 v2 = *(const f32x4*)(base + (size_t)(p + 2) * ENC_DIM);
        const f32x4 v3 = *(const f32x4*)(base + (size_t)(p + 3) * ENC_DIM);
        a0 += as[p + 0] * v0; a1 += as[p + 1] * v1;
        a2 += as[p + 2] * v2; a3 += as[p + 3] * v3;
    }
    const f32x4 v48 = *(const f32x4*)(base + (size_t)48 * ENC_DIM);
    const f32x4 r = ((a0 + a1) + (a2 + a3)) + as[48] * v48;
    float* dst = &awe[(size_t)b * ENC_DIM + e0];
    atomicAdd(dst + 0, r[0]);
    atomicAdd(dst + 1, r[1]);
    atomicAdd(dst + 2, r[2]);
    atomicAdd(dst + 3, r[3]);
}

// ----------------------------------------------------------------
extern "C" void kernel_launch(void* const* d_in, const int* in_sizes, int n_in,
                              void* d_out, int out_size, void* d_ws, size_t ws_size,
                              hipStream_t stream) {
    const float* enc    = (const float*)d_in[0];   // [128,196,2048]
    const float* dh     = (const float*)d_in[1];   // [128,512]
    const float* W_enc  = (const float*)d_in[2];   // [2048,512]
    const float* b_enc  = (const float*)d_in[3];   // [512]
    const float* W_dec  = (const float*)d_in[4];   // [512,512]
    const float* b_dec  = (const float*)d_in[5];   // [512]
    const float* W_full = (const float*)d_in[6];   // [512]
    const float* b_full = (const float*)d_in[7];   // scalar

    float* awe   = (float*)d_out;                  // [128,2048]
    float* alpha = awe + BATCH * ENC_DIM;          // [128,196]; also score scratch

    // workspace: Wt bf16 (2 MB) + att2' fp32 (256 KB) = 2.25 MB
    unsigned short* Wt   = (unsigned short*)d_ws;
    float*          att2 = (float*)((char*)d_ws + (size_t)ATT_DIM * ENC_DIM * 2);

    k0_transpose<<<dim3(8, 32),      256, 0, stream>>>(W_enc, Wt);
    k1_att2     <<<128,              256, 0, stream>>>(dh, W_dec, b_dec, b_enc, b_full, att2, alpha, awe);
    k2_gemm     <<<dim3(4, 196),     256, 0, stream>>>(enc, Wt, att2, W_full, alpha);
    k3_softmax  <<<128,              256, 0, stream>>>(alpha);
    k4_awe      <<<dim3(2, 4, 128),  256, 0, stream>>>(enc, alpha, awe);
}

// Round 3
// 435.085 us; speedup vs baseline: 1.3655x; 1.3655x over previous
//
#include <hip/hip_runtime.h>
#include <hip/hip_bf16.h>

#define ENC_DIM 2048
#define DEC_DIM 512
#define ATT_DIM 512
#define BATCH   128
#define NPIX    196
#define NROWS   (BATCH * NPIX)   // 25088

typedef short bf16x8 __attribute__((ext_vector_type(8)));
typedef float f32x4  __attribute__((ext_vector_type(4)));
typedef unsigned short u16x8 __attribute__((ext_vector_type(8)));

__device__ __forceinline__ unsigned short f2bf(float f) {
    union { float f; unsigned u; } v; v.f = f;
    unsigned r = v.u + 0x7fffu + ((v.u >> 16) & 1u);   // RNE
    return (unsigned short)(r >> 16);
}

// ---------------------------------------------------------------- k0:
// Wt[a][e] = bf16(W_enc[e][a])  (2048x512 -> 512x2048), LDS-tiled transpose.
__global__ void k0_transpose(const float* __restrict__ W_enc,
                             unsigned short* __restrict__ Wt) {
    __shared__ float ts[64][65];
    const int a0 = blockIdx.x * 64;      // grid.x = 8
    const int e0 = blockIdx.y * 64;      // grid.y = 32
    const int tx = threadIdx.x & 15;
    const int ty = threadIdx.x >> 4;     // 16x16 threads
    #pragma unroll
    for (int p = 0; p < 4; ++p) {
        const int e = ty + p * 16;
        const float4 v = *(const float4*)&W_enc[(size_t)(e0 + e) * ATT_DIM + a0 + tx * 4];
        ts[e][tx * 4 + 0] = v.x; ts[e][tx * 4 + 1] = v.y;
        ts[e][tx * 4 + 2] = v.z; ts[e][tx * 4 + 3] = v.w;
    }
    __syncthreads();
    #pragma unroll
    for (int p = 0; p < 4; ++p) {
        const int a = ty + p * 16;
        ushort4 u;
        u.x = f2bf(ts[tx * 4 + 0][a]);
        u.y = f2bf(ts[tx * 4 + 1][a]);
        u.z = f2bf(ts[tx * 4 + 2][a]);
        u.w = f2bf(ts[tx * 4 + 3][a]);
        *(ushort4*)&Wt[(size_t)(a0 + a) * ENC_DIM + e0 + tx * 4] = u;
    }
}

// ---------------------------------------------------------------- k1:
// att2'[b][a] = dh[b,:]@W_dec[:,a] + b_dec[a] + b_enc[a];  att[r] = b_full.
__global__ void k1_att2(const float* __restrict__ dh, const float* __restrict__ W_dec,
                        const float* __restrict__ b_dec, const float* __restrict__ b_enc,
                        const float* __restrict__ b_full,
                        float* __restrict__ att2, float* __restrict__ att) {
    __shared__ float dhs[DEC_DIM];
    const int b = blockIdx.x, t = threadIdx.x;   // 128 blocks x 256 thr
    dhs[t]       = dh[b * DEC_DIM + t];
    dhs[t + 256] = dh[b * DEC_DIM + t + 256];
    __syncthreads();
    float acc0 = 0.f, acc1 = 0.f;
    for (int d = 0; d < DEC_DIM; ++d) {
        const float h = dhs[d];
        acc0 += h * W_dec[d * ATT_DIM + t];
        acc1 += h * W_dec[d * ATT_DIM + t + 256];
    }
    att2[b * ATT_DIM + t]       = acc0 + b_dec[t]       + b_enc[t];
    att2[b * ATT_DIM + t + 256] = acc1 + b_dec[t + 256] + b_enc[t + 256];
    const int gid = b * 256 + t;
    if (gid < NROWS) att[gid] = b_full[0];
}

// ---------------------------------------------------------------- k2:
// Fused bf16 MFMA GEMM + relu + W_full reduction -> atomic partial scores.
// BM=64, BN=128, BK=64. grid (4 n-tiles, 392 m-tiles) = 1568 blocks.
// LDS row stride 72 shorts (144 B = 9*16 B, odd multiple of 16 -> phase-
// conflict-free b128 reads AND writes).
__launch_bounds__(256, 4)
__global__ void k2_gemm(const float* __restrict__ enc, const unsigned short* __restrict__ Wt,
                        const float* __restrict__ att2, const float* __restrict__ W_full,
                        float* __restrict__ att) {
    __shared__ __align__(16) unsigned short As[64 * 72];
    __shared__ __align__(16) unsigned short Bs[128 * 72];
    __shared__ float att2s[2][128];
    __shared__ float wfs[128];

    const int t    = threadIdx.x;
    const int n0   = blockIdx.x * 128;
    const int row0 = blockIdx.y * 64;
    const int b0   = row0 / NPIX;
    const int rows_left = (b0 + 1) * NPIX - row0;   // rows in this tile with batch b0

    if (t < 128) {
        att2s[0][t] = att2[b0 * ATT_DIM + n0 + t];
        att2s[1][t] = (b0 + 1 < BATCH) ? att2[(b0 + 1) * ATT_DIM + n0 + t] : 0.f;
        wfs[t]      = W_full[n0 + t];
    }

    const int w    = t >> 6;         // wave 0..3
    const int lane = t & 63;
    const int q    = lane >> 4;      // 0..3
    const int cl   = lane & 15;
    const int wm   = (w >> 1) * 32;  // wave's row offset (0/32)
    const int wn   = (w & 1) * 64;   // wave's col offset (0/64)

    f32x4 acc[2][4] = {};

    // staging assignments (BK=64)
    const int ar = t >> 3;           // A row 0..31 (+32 second pass)
    const int ak = (t & 7) * 8;      // A k 0..56 (8 floats per thread-row)
    const int bn = t >> 2;           // B row 0..63 (+64 second pass)
    const int bk = (t & 3) * 16;     // B k 0,16,32,48 (16 bf16 per thread-row)

    const float*          encA = enc + (size_t)(row0 + ar) * ENC_DIM + ak;
    const unsigned short* WtB  = Wt  + (size_t)(n0 + bn)   * ENC_DIM + bk;

    for (int k0 = 0; k0 < ENC_DIM; k0 += 64) {
        __syncthreads();   // previous iteration's frag reads complete
        // stage A (fp32 -> bf16): 64 x 64
        #pragma unroll
        for (int p = 0; p < 2; ++p) {
            const float4 v0 = *(const float4*)(encA + (size_t)p * 32 * ENC_DIM + k0);
            const float4 v1 = *(const float4*)(encA + (size_t)p * 32 * ENC_DIM + k0 + 4);
            u16x8 u;
            u[0] = f2bf(v0.x); u[1] = f2bf(v0.y); u[2] = f2bf(v0.z); u[3] = f2bf(v0.w);
            u[4] = f2bf(v1.x); u[5] = f2bf(v1.y); u[6] = f2bf(v1.z); u[7] = f2bf(v1.w);
            *(u16x8*)&As[(ar + p * 32) * 72 + ak] = u;
        }
        // stage B (bf16): 128 x 64
        #pragma unroll
        for (int p = 0; p < 2; ++p) {
            const uint4 v0 = *(const uint4*)(WtB + (size_t)p * 64 * ENC_DIM + k0);
            const uint4 v1 = *(const uint4*)(WtB + (size_t)p * 64 * ENC_DIM + k0 + 8);
            *(uint4*)&Bs[(bn + p * 64) * 72 + bk]     = v0;
            *(uint4*)&Bs[(bn + p * 64) * 72 + bk + 8] = v1;
        }
        __syncthreads();   // tile visible

        #pragma unroll
        for (int h = 0; h < 2; ++h) {   // two 32-wide K halves
            bf16x8 af[2], bfr[4];
            #pragma unroll
            for (int i = 0; i < 2; ++i)
                af[i]  = *(const bf16x8*)&As[(wm + i * 16 + cl) * 72 + h * 32 + q * 8];
            #pragma unroll
            for (int i = 0; i < 4; ++i)
                bfr[i] = *(const bf16x8*)&Bs[(wn + i * 16 + cl) * 72 + h * 32 + q * 8];
            #pragma unroll
            for (int mi = 0; mi < 2; ++mi)
                #pragma unroll
                for (int ni = 0; ni < 4; ++ni)
                    acc[mi][ni] = __builtin_amdgcn_mfma_f32_16x16x32_bf16(
                        af[mi], bfr[ni], acc[mi][ni], 0, 0, 0);
        }
    }

    // Epilogue: relu(att1 + att2') * W_full, reduce over this block's 128 cols.
    #pragma unroll
    for (int mi = 0; mi < 2; ++mi) {
        float rs[4];
        #pragma unroll
        for (int i = 0; i < 4; ++i) {
            const int lr  = wm + mi * 16 + q * 4 + i;         // local row
            const int sel = (lr >= rows_left) ? 1 : 0;
            float sum = 0.f;
            #pragma unroll
            for (int ni = 0; ni < 4; ++ni) {
                const int j = wn + ni * 16 + cl;              // local col 0..127
                float v = acc[mi][ni][i] + att2s[sel][j];
                v = fmaxf(v, 0.f);
                sum += v * wfs[j];
            }
            rs[i] = sum;
        }
        #pragma unroll
        for (int o = 1; o < 16; o <<= 1) {
            #pragma unroll
            for (int i = 0; i < 4; ++i) rs[i] += __shfl_xor(rs[i], o);
        }
        if (cl == 0) {
            #pragma unroll
            for (int i = 0; i < 4; ++i) {
                const int r = row0 + wm + mi * 16 + q * 4 + i;
                atomicAdd(&att[r], rs[i]);
            }
        }
    }
}

// ---------------------------------------------------------------- k3:
// softmax over P=196, in place. 128 blocks x 256 thr.
__global__ void k3_softmax(float* __restrict__ att_alpha) {
    __shared__ float red[4];
    const int b = blockIdx.x, t = threadIdx.x;
    const int w = t >> 6, lane = t & 63;
    const float x = (t < NPIX) ? att_alpha[b * NPIX + t] : -INFINITY;
    float m = x;
    #pragma unroll
    for (int o = 32; o >= 1; o >>= 1) m = fmaxf(m, __shfl_xor(m, o));
    if (lane == 0) red[w] = m;
    __syncthreads();
    m = fmaxf(fmaxf(red[0], red[1]), fmaxf(red[2], red[3]));
    const float e = (t < NPIX) ? __expf(x - m) : 0.f;
    float s = e;
    #pragma unroll
    for (int o = 32; o >= 1; o >>= 1) s += __shfl_xor(s, o);
    __syncthreads();
    if (lane == 0) red[w] = s;
    __syncthreads();
    s = red[0] + red[1] + red[2] + red[3];
    if (t < NPIX) att_alpha[b * NPIX + t] = e / s;
}

// ---------------------------------------------------------------- k4:
// awe[b][e] = sum_p alpha[b][p] * enc[b][p][e].
// grid (4 e-chunks, 128 b) x 128 thr; each thread owns one float4 strip,
// 8 independent accumulators -> 8 loads in flight per lane.
__global__ void k4_awe(const float* __restrict__ enc, const float* __restrict__ alpha,
                       float* __restrict__ awe) {
    __shared__ float as[NPIX];
    const int b  = blockIdx.y;
    const int t  = threadIdx.x;
    const int e0 = blockIdx.x * 512 + t * 4;
    as[t] = alpha[b * NPIX + t];
    if (t < NPIX - 128) as[t + 128] = alpha[b * NPIX + t + 128];
    __syncthreads();
    const float* base = enc + (size_t)b * NPIX * ENC_DIM + e0;
    f32x4 a[8] = {};
    for (int p = 0; p < 192; p += 8) {
        #pragma unroll
        for (int j = 0; j < 8; ++j) {
            const f32x4 v = *(const f32x4*)(base + (size_t)(p + j) * ENC_DIM);
            a[j] += as[p + j] * v;
        }
    }
    #pragma unroll
    for (int j = 0; j < 4; ++j) {
        const f32x4 v = *(const f32x4*)(base + (size_t)(192 + j) * ENC_DIM);
        a[j] += as[192 + j] * v;
    }
    const f32x4 r = ((a[0] + a[1]) + (a[2] + a[3])) + ((a[4] + a[5]) + (a[6] + a[7]));
    *(f32x4*)&awe[(size_t)b * ENC_DIM + e0] = r;
}

// ----------------------------------------------------------------
extern "C" void kernel_launch(void* const* d_in, const int* in_sizes, int n_in,
                              void* d_out, int out_size, void* d_ws, size_t ws_size,
                              hipStream_t stream) {
    const float* enc    = (const float*)d_in[0];   // [128,196,2048]
    const float* dh     = (const float*)d_in[1];   // [128,512]
    const float* W_enc  = (const float*)d_in[2];   // [2048,512]
    const float* b_enc  = (const float*)d_in[3];   // [512]
    const float* W_dec  = (const float*)d_in[4];   // [512,512]
    const float* b_dec  = (const float*)d_in[5];   // [512]
    const float* W_full = (const float*)d_in[6];   // [512]
    const float* b_full = (const float*)d_in[7];   // scalar

    float* awe   = (float*)d_out;                  // [128,2048]
    float* alpha = awe + BATCH * ENC_DIM;          // [128,196]; also score scratch

    // workspace: Wt bf16 (2 MB) + att2' fp32 (256 KB) = 2.25 MB
    unsigned short* Wt   = (unsigned short*)d_ws;
    float*          att2 = (float*)((char*)d_ws + (size_t)ATT_DIM * ENC_DIM * 2);

    k0_transpose<<<dim3(8, 32),  256, 0, stream>>>(W_enc, Wt);
    k1_att2     <<<128,          256, 0, stream>>>(dh, W_dec, b_dec, b_enc, b_full, att2, alpha);
    k2_gemm     <<<dim3(4, 392), 256, 0, stream>>>(enc, Wt, att2, W_full, alpha);
    k3_softmax  <<<128,          256, 0, stream>>>(alpha);
    k4_awe      <<<dim3(4, 128), 128, 0, stream>>>(enc, alpha, awe);
}